// Round 17
// baseline (107.775 us; speedup 1.0000x reference)
//
#include <hip/hip_runtime.h>
#include <hip/hip_bf16.h>

typedef __attribute__((ext_vector_type(8))) short short8;
typedef __attribute__((ext_vector_type(4))) float f32x4;
typedef __attribute__((ext_vector_type(4))) unsigned short ush4;

typedef const __attribute__((address_space(1))) void* gas_p;
typedef __attribute__((address_space(3))) void* las_p;
#define GLOAD_LDS16(g, l) __builtin_amdgcn_global_load_lds((gas_p)(const void*)(g), (las_p)(void*)(l), 16, 0, 0)

__device__ __forceinline__ unsigned short f2bf(float f) {
    union { float f; unsigned int u; } v; v.f = f;
    unsigned int r = v.u + 0x7FFFu + ((v.u >> 16) & 1u);
    return (unsigned short)(r >> 16);
}
__device__ __forceinline__ unsigned pk2(float a, float b) {
    return (unsigned)f2bf(a) | ((unsigned)f2bf(b) << 16);
}

// ---------------- weight cast + transpose only (x is consumed f32 by QKV) ----------------
// blocks [0,1728): Wqkv [384][1152] -> wqkvt [1152][384]
// blocks [1728,2304): Wproj [384][384] -> wprojt [384][384]
__global__ __launch_bounds__(256) void cast_w_kernel(
    const float* __restrict__ Wqkv, const float* __restrict__ Wproj,
    unsigned short* __restrict__ wqkvt, unsigned short* __restrict__ wprojt)
{
    const int bid = blockIdx.x;
    if (bid < 1728) {
        int idx = bid * 256 + threadIdx.x;             // < 1152*384
        int n = idx / 384, k = idx - n * 384;
        wqkvt[idx] = f2bf(Wqkv[(size_t)k * 1152 + n]);
    } else {
        int idx = (bid - 1728) * 256 + threadIdx.x;    // < 384*384
        int n = idx / 384, k = idx - n * 384;
        wprojt[idx] = f2bf(Wproj[(size_t)k * 384 + n]);
    }
}

// ---------------- QKV GEMM, A read DIRECT as f32: C = x[M][384] * Wt[1152][384]^T ----------------
// 128x128 tile, 4 waves, BK=64, round-12 sync structure (single-buffer, 2 barriers).
// A staged RAW f32 via global_load_lds (async, linear dest, pre-swizzled 16B source
// chunks); bf16 conversion happens at FRAGMENT READ (2x ds_read_b128 +
// 4x v_cvt_pk_bf16_f32 per frag) — cast off the serial path, pipelined with MFMA.
// B staged bf16 exactly as round 12. LDS: Af 32KB | Bs 16KB = 48KB.
// Epilogue: n<768 -> qkb scalar stores (r12); n>=768 -> vtb via LDS transpose.
__global__ __launch_bounds__(256, 2) void gemm_qkv_kernel(
    const float* __restrict__ x,              // [32768][384] f32
    const unsigned short* __restrict__ Bt,    // wqkvt [1152][384] bf16
    unsigned short* __restrict__ qkb,         // [32768][768]
    unsigned short* __restrict__ vtb)         // [768][64][256]
{
    const int K = 384;
    __shared__ __align__(16) char Sh[48 * 1024];   // Af (32KB f32) | Bs (16KB bf16)
    char* Af = Sh;
    char* Bs = Sh + 32768;
    const int tid = threadIdx.x;
    const int lane = tid & 63, wv = tid >> 6;
    const int c = lane & 15, g = lane >> 4;
    const int wm = (wv >> 1) * 64, wn = (wv & 1) * 64;

    // XCD-chunked remap, n-fastest (grid = 2304 = 8 x 32 x 9)
    const int id = blockIdx.x, xcd = id & 7, kk = id >> 3;
    const long m0 = (long)(xcd * 32 + kk / 9) * 128;
    const long n0 = (long)(kk % 9) * 128;

    f32x4 acc[4][4] = {};
    const int xr = (c & 7) << 4;

    for (int kt = 0; kt < K; kt += 64) {
        // A: f32 rows (256B), 2048 chunks of 16B; source chunk pre-swizzled cc^(row&7)
        #pragma unroll
        for (int i = 0; i < 8; ++i) {
            int ch = i * 256 + wv * 64 + lane;
            int row = ch >> 4, cc = ch & 15;
            GLOAD_LDS16(&x[(m0 + row) * (size_t)K + kt + ((cc ^ (row & 7)) << 2)],
                        Af + (i * 256 + wv * 64) * 16);
        }
        // B: bf16 rows (128B), 1024 chunks of 16B (round-12 path)
        #pragma unroll
        for (int i = 0; i < 4; ++i) {
            int ch = i * 256 + wv * 64 + lane;
            int row = ch >> 3, cc = ch & 7;
            GLOAD_LDS16(&Bt[(n0 + row) * (size_t)K + kt + ((cc ^ (row & 7)) << 3)],
                        Bs + (i * 256 + wv * 64) * 16);
        }
        __syncthreads();
        #pragma unroll
        for (int ks = 0; ks < 2; ++ks) {
            short8 af[4], bf_[4];
            #pragma unroll
            for (int i = 0; i < 4; ++i) {
                int row = wm + i * 16 + c;               // row&7 == c&7
                int ch0 = ks * 8 + g * 2;                // k-chunk (4 f32 each)
                f32x4 lo = *(const f32x4*)(Af + row * 256 + ((ch0 ^ (c & 7)) << 4));
                f32x4 hi = *(const f32x4*)(Af + row * 256 + (((ch0 + 1) ^ (c & 7)) << 4));
                unsigned r0, r1, r2, r3;
                asm("v_cvt_pk_bf16_f32 %0, %1, %2" : "=v"(r0) : "v"(lo[0]), "v"(lo[1]));
                asm("v_cvt_pk_bf16_f32 %0, %1, %2" : "=v"(r1) : "v"(lo[2]), "v"(lo[3]));
                asm("v_cvt_pk_bf16_f32 %0, %1, %2" : "=v"(r2) : "v"(hi[0]), "v"(hi[1]));
                asm("v_cvt_pk_bf16_f32 %0, %1, %2" : "=v"(r3) : "v"(hi[2]), "v"(hi[3]));
                union { uint4 u4; short8 s8; } cv;
                cv.u4.x = r0; cv.u4.y = r1; cv.u4.z = r2; cv.u4.w = r3;
                af[i] = cv.s8;
            }
            #pragma unroll
            for (int i = 0; i < 4; ++i)
                bf_[i] = *(const short8*)(Bs +
                    (((wn + i * 16 + c) * 128 + (ks * 32 + g * 8) * 2) ^ xr));
            #pragma unroll
            for (int mi = 0; mi < 4; ++mi)
                #pragma unroll
                for (int ni = 0; ni < 4; ++ni)
                    acc[mi][ni] = __builtin_amdgcn_mfma_f32_16x16x32_bf16(
                        af[mi], bf_[ni], acc[mi][ni], 0, 0, 0);
        }
        __syncthreads();
    }

    if (n0 < 768) {
        #pragma unroll
        for (int mi = 0; mi < 4; ++mi)
            #pragma unroll
            for (int ni = 0; ni < 4; ++ni)
                #pragma unroll
                for (int r = 0; r < 4; ++r) {
                    long m = m0 + wm + mi * 16 + g * 4 + r;
                    long n = n0 + wn + ni * 16 + c;
                    qkb[m * 768 + n] = f2bf(acc[mi][ni][r]);
                }
    } else {
        // V block: transpose 64x64 wave subtile via private LDS region, store coalesced
        char* wbase = Af + wv * 8192;            // Af dead after final barrier
        #pragma unroll
        for (int ni = 0; ni < 4; ++ni)
            #pragma unroll
            for (int mi = 0; mi < 4; ++mi)
                #pragma unroll
                for (int r = 0; r < 4; ++r) {
                    int d = ni * 16 + c, t = mi * 16 + g * 4 + r;
                    int byte = (d * 128 + t * 2) ^ ((d & 7) << 4);
                    *(unsigned short*)(wbase + byte) = f2bf(acc[mi][ni][r]);
                }
        __asm__ __volatile__("" ::: "memory");
        int h = (int)((n0 + wn - 768) >> 6);
        long b = (m0 + wm) >> 8;
        int t0 = (int)((m0 + wm) & 255);
        long bh = b * 6 + h;
        #pragma unroll
        for (int it = 0; it < 8; ++it) {
            int d = it * 8 + (lane >> 3), ck = lane & 7;
            short8 v = *(const short8*)(wbase + ((d * 128 + ck * 16) ^ ((d & 7) << 4)));
            *(short8*)&vtb[(bh * 64 + d) * 256 + t0 + ck * 8] = v;
        }
    }
}

// ---------------- proj GEMM: C[M][N] f32 = A[M][K] bf16 * Bt[N][K]^T (round-12 structure) ----------------
template<int NP>
__global__ __launch_bounds__(256, 2) void gemm_proj_kernel(
    const unsigned short* __restrict__ A, const unsigned short* __restrict__ Bt,
    float* __restrict__ C, int M, int N, int K)
{
    __shared__ __align__(16) unsigned short As[128 * 64];
    __shared__ __align__(16) unsigned short Bs[128 * 64];
    const int tid = threadIdx.x;
    const int lane = tid & 63, wv = tid >> 6;
    const int c = lane & 15, g = lane >> 4;
    const int wm = (wv >> 1) * 64, wn = (wv & 1) * 64;

    const int mpx = (M >> 7) >> 3;
    const int id = blockIdx.x, xcd = id & 7, kk = id >> 3;
    const long m0 = (long)(xcd * mpx + kk / NP) * 128;
    const long n0 = (long)(kk % NP) * 128;

    f32x4 acc[4][4] = {};
    const int xr = (c & 7) << 4;

    for (int kt = 0; kt < K; kt += 64) {
        #pragma unroll
        for (int i = 0; i < 4; ++i) {
            int ch = i * 256 + wv * 64 + lane;
            int row = ch >> 3, cc = ch & 7;
            int sc = (cc ^ (row & 7)) * 8;
            GLOAD_LDS16(&A[(m0 + row) * (size_t)K + kt + sc],
                        &As[(i * 256 + wv * 64) * 8]);
            GLOAD_LDS16(&Bt[(n0 + row) * (size_t)K + kt + sc],
                        &Bs[(i * 256 + wv * 64) * 8]);
        }
        __syncthreads();
        #pragma unroll
        for (int ks = 0; ks < 2; ++ks) {
            short8 af[4], bf_[4];
            #pragma unroll
            for (int i = 0; i < 4; ++i)
                af[i] = *(const short8*)((char*)As +
                    (((wm + i * 16 + c) * 128 + (ks * 32 + g * 8) * 2) ^ xr));
            #pragma unroll
            for (int i = 0; i < 4; ++i)
                bf_[i] = *(const short8*)((char*)Bs +
                    (((wn + i * 16 + c) * 128 + (ks * 32 + g * 8) * 2) ^ xr));
            #pragma unroll
            for (int mi = 0; mi < 4; ++mi)
                #pragma unroll
                for (int ni = 0; ni < 4; ++ni)
                    acc[mi][ni] = __builtin_amdgcn_mfma_f32_16x16x32_bf16(
                        af[mi], bf_[ni], acc[mi][ni], 0, 0, 0);
        }
        __syncthreads();
    }

    #pragma unroll
    for (int mi = 0; mi < 4; ++mi)
        #pragma unroll
        for (int ni = 0; ni < 4; ++ni)
            #pragma unroll
            for (int r = 0; r < 4; ++r) {
                long m = m0 + wm + mi * 16 + g * 4 + r;
                long n = n0 + wn + ni * 16 + c;
                C[m * N + n] = acc[mi][ni][r];
            }
}

// ---------------- fused causal attention: one block per (b,h), transposed pipeline ----------------
__global__ __launch_bounds__(256, 3) void attn_kernel(
    const unsigned short* __restrict__ qk,    // [B*T][768] bf16 (q|k)
    const unsigned short* __restrict__ vt,    // [B*6+h][64 d][256 tok] bf16
    unsigned short* __restrict__ outp)        // [B*T][384] bf16
{
    const int bh = blockIdx.x;
    const int b = bh / 6, h = bh - b * 6;
    const int tid = threadIdx.x;
    const int lane = tid & 63, wv = tid >> 6;
    const int c = lane & 15, g = lane >> 4;

    __shared__ unsigned short Ks[256 * 64];    // [key][d], swizzled, 32 KB
    __shared__ unsigned short Pl[4][16 * 64];  // per-wave P [q=c][k], 8 KB

    #pragma unroll
    for (int it = 0; it < 8; ++it) {
        int ch = it * 256 + tid;
        int row = ch >> 3, col = (ch & 7) * 8;
        int db = (row * 128 + col * 2) ^ ((row & 7) << 4);
        *(short8*)((char*)Ks + db) =
            *(const short8*)&qk[(size_t)(b * 256 + row) * 768 + 384 + h * 64 + col];
    }
    __syncthreads();

    char* plw = (char*)Pl[wv];

    for (int t = 0; t < 2; ++t) {
        const int p = t ? 7 - wv : wv;
        const int jlast = p >> 1;
        const int modd = (p & 1) * 32;
        const int qt0 = p * 32;

        short8 aq[2][2];
        #pragma unroll
        for (int mi = 0; mi < 2; ++mi)
            #pragma unroll
            for (int ks = 0; ks < 2; ++ks)
                aq[mi][ks] = *(const short8*)&qk[
                    (size_t)(b * 256 + qt0 + mi * 16 + c) * 768 + h * 64 + ks * 32 + g * 8];

        f32x4 o[2][4] = {};
        float mrun[2] = {-1e30f, -1e30f}, lrun[2] = {0.f, 0.f};

        for (int j = 0; j <= jlast; ++j) {
            short8 bv[4][2];
            #pragma unroll
            for (int nd = 0; nd < 4; ++nd)
                #pragma unroll
                for (int ks = 0; ks < 2; ++ks)
                    bv[nd][ks] = *(const short8*)&vt[
                        ((size_t)bh * 64 + nd * 16 + c) * 256 + j * 64 + ks * 32 + g * 8];

            short8 bk[4][2];
            #pragma unroll
            for (int ni = 0; ni < 4; ++ni)
                #pragma unroll
                for (int ks = 0; ks < 2; ++ks) {
                    int key = j * 64 + ni * 16 + c;
                    bk[ni][ks] = *(const short8*)((char*)Ks +
                        ((key * 128 + (ks * 32 + g * 8) * 2) ^ ((key & 7) << 4)));
                }

            #pragma unroll
            for (int mi = 0; mi < 2; ++mi) {
                float pv[4][4];
                #pragma unroll
                for (int ni = 0; ni < 4; ++ni) {
                    f32x4 z = {0.f, 0.f, 0.f, 0.f};
                    z = __builtin_amdgcn_mfma_f32_16x16x32_bf16(bk[ni][0], aq[mi][0], z, 0, 0, 0);
                    z = __builtin_amdgcn_mfma_f32_16x16x32_bf16(bk[ni][1], aq[mi][1], z, 0, 0, 0);
                    #pragma unroll
                    for (int r = 0; r < 4; ++r) {
                        float v = z[r] * 0.125f;
                        if (j == jlast) {
                            int kloc = ni * 16 + g * 4 + r;
                            int qloc = mi * 16 + c + modd;
                            if (kloc > qloc) v = -1e30f;
                        }
                        pv[ni][r] = v;
                    }
                }
                float m01 = fmaxf(fmaxf(pv[0][0], pv[0][1]), fmaxf(pv[0][2], pv[0][3]));
                float m11 = fmaxf(fmaxf(pv[1][0], pv[1][1]), fmaxf(pv[1][2], pv[1][3]));
                float m21 = fmaxf(fmaxf(pv[2][0], pv[2][1]), fmaxf(pv[2][2], pv[2][3]));
                float m31 = fmaxf(fmaxf(pv[3][0], pv[3][1]), fmaxf(pv[3][2], pv[3][3]));
                float m1 = fmaxf(fmaxf(m01, m11), fmaxf(m21, m31));
                m1 = fmaxf(m1, __shfl_xor(m1, 16));
                m1 = fmaxf(m1, __shfl_xor(m1, 32));
                float mold = mrun[mi];
                float mnew = fmaxf(mold, m1);
                float fac = __expf(mold - mnew);
                float ssum = 0.f;
                #pragma unroll
                for (int ni = 0; ni < 4; ++ni)
                    #pragma unroll
                    for (int r = 0; r < 4; ++r) {
                        float pp = __expf(pv[ni][r] - mnew);
                        pv[ni][r] = pp;
                        ssum += pp;
                    }
                ssum += __shfl_xor(ssum, 16);
                ssum += __shfl_xor(ssum, 32);
                lrun[mi] = lrun[mi] * fac + ssum;
                mrun[mi] = mnew;
                #pragma unroll
                for (int nd = 0; nd < 4; ++nd)
                    #pragma unroll
                    for (int r = 0; r < 4; ++r) o[mi][nd][r] *= fac;

                __asm__ __volatile__("" ::: "memory");
                #pragma unroll
                for (int ni = 0; ni < 4; ++ni) {
                    uint2 w;
                    w.x = pk2(pv[ni][0], pv[ni][1]);
                    w.y = pk2(pv[ni][2], pv[ni][3]);
                    *(uint2*)(plw + ((c * 128 + ni * 32 + g * 8) ^ ((c & 7) << 4))) = w;
                }
                __asm__ __volatile__("" ::: "memory");

                short8 ap[2];
                #pragma unroll
                for (int ks = 0; ks < 2; ++ks)
                    ap[ks] = *(const short8*)(plw +
                        ((c * 128 + ks * 64 + g * 16) ^ ((c & 7) << 4)));

                #pragma unroll
                for (int nd = 0; nd < 4; ++nd) {
                    o[mi][nd] = __builtin_amdgcn_mfma_f32_16x16x32_bf16(bv[nd][0], ap[0], o[mi][nd], 0, 0, 0);
                    o[mi][nd] = __builtin_amdgcn_mfma_f32_16x16x32_bf16(bv[nd][1], ap[1], o[mi][nd], 0, 0, 0);
                }
                __asm__ __volatile__("" ::: "memory");
            }
        }

        #pragma unroll
        for (int mi = 0; mi < 2; ++mi) {
            float inv = 1.0f / lrun[mi];
            #pragma unroll
            for (int nd = 0; nd < 4; ++nd) {
                ush4 w;
                #pragma unroll
                for (int r = 0; r < 4; ++r) w[r] = f2bf(o[mi][nd][r] * inv);
                *(ush4*)&outp[((size_t)b * 256 + qt0 + mi * 16 + c) * 384 + h * 64 + nd * 16 + g * 4] = w;
            }
        }
    }
}

extern "C" void kernel_launch(void* const* d_in, const int* in_sizes, int n_in,
                              void* d_out, int out_size, void* d_ws, size_t ws_size,
                              hipStream_t stream) {
    const float* x     = (const float*)d_in[0];   // [128,256,384] f32
    const float* Wqkv  = (const float*)d_in[1];   // [384,1152] f32
    const float* Wproj = (const float*)d_in[2];   // [384,384] f32

    char* ws = (char*)d_ws;
    unsigned short* wqkvt  = (unsigned short*)(ws);                 //    884,736 B
    unsigned short* wprojt = (unsigned short*)(ws + 884736);        //    294,912 B
    unsigned short* qkb    = (unsigned short*)(ws + 1179648);       // 50,331,648 B  [tok][768]
    unsigned short* vtb    = (unsigned short*)(ws + 51511296);      // 25,165,824 B  [bh][64][256]
    unsigned short* attnb  = (unsigned short*)(ws + 76677120);      // 25,165,824 B
    // total: 101,842,944 B

    cast_w_kernel<<<2304, 256, 0, stream>>>(Wqkv, Wproj, wqkvt, wprojt);

    gemm_qkv_kernel<<<2304, 256, 0, stream>>>(x, wqkvt, qkb, vtb);
    attn_kernel<<<768, 256, 0, stream>>>(qkb, vtb, attnb);
    gemm_proj_kernel<3><<<768, 256, 0, stream>>>(attnb, wprojt, (float*)d_out, 32768, 384, 384);
}

// Round 18
// 105.164 us; speedup vs baseline: 1.0248x; 1.0248x over previous
//
#include <hip/hip_runtime.h>
#include <hip/hip_bf16.h>

typedef __attribute__((ext_vector_type(8))) short short8;
typedef __attribute__((ext_vector_type(4))) float f32x4;
typedef __attribute__((ext_vector_type(4))) unsigned short ush4;

typedef const __attribute__((address_space(1))) void* gas_p;
typedef __attribute__((address_space(3))) void* las_p;
#define GLOAD_LDS16(g, l) __builtin_amdgcn_global_load_lds((gas_p)(const void*)(g), (las_p)(void*)(l), 16, 0, 0)

__device__ __forceinline__ unsigned short f2bf(float f) {
    union { float f; unsigned int u; } v; v.f = f;
    unsigned int r = v.u + 0x7FFFu + ((v.u >> 16) & 1u);
    return (unsigned short)(r >> 16);
}
__device__ __forceinline__ unsigned pk2(float a, float b) {
    return (unsigned)f2bf(a) | ((unsigned)f2bf(b) << 16);
}

// ---------------- merged prologue cast: x (vectorized) + both weight transposes ----------------
__global__ __launch_bounds__(256) void cast_all_kernel(
    const float* __restrict__ x, const float* __restrict__ Wqkv, const float* __restrict__ Wproj,
    unsigned short* __restrict__ xb, unsigned short* __restrict__ wqkvt,
    unsigned short* __restrict__ wprojt)
{
    const int bid = blockIdx.x;
    if (bid < 6144) {
        int i = bid * 256 + threadIdx.x;           // < 1572864
        const float4* p = (const float4*)x + (size_t)i * 2;
        float4 a = p[0], b = p[1];
        short8 o;
        o[0] = (short)f2bf(a.x); o[1] = (short)f2bf(a.y);
        o[2] = (short)f2bf(a.z); o[3] = (short)f2bf(a.w);
        o[4] = (short)f2bf(b.x); o[5] = (short)f2bf(b.y);
        o[6] = (short)f2bf(b.z); o[7] = (short)f2bf(b.w);
        *(short8*)(xb + (size_t)i * 8) = o;
    } else if (bid < 7872) {
        int idx = (bid - 6144) * 256 + threadIdx.x;    // < 1152*384
        int n = idx / 384, k = idx - n * 384;
        wqkvt[idx] = f2bf(Wqkv[(size_t)k * 1152 + n]);
    } else {
        int idx = (bid - 7872) * 256 + threadIdx.x;    // < 384*384
        int n = idx / 384, k = idx - n * 384;
        wprojt[idx] = f2bf(Wproj[(size_t)k * 384 + n]);
    }
}

// ---------------- GEMM: C = A[M][K] * Bt[N][K]^T, bf16 MFMA ----------------
// 128x128 tile, 4 waves (2x2 of 64x64), BK=64. B double-buffered global_load_lds
// (issued pre-compute); A single-buffered, staged between the two barriers.
// LDS 48 KB. Pre-swizzled source columns + XOR frag reads. XCD-chunked grid,
// n-fastest in chunk (A-panel L2 reuse; FETCH ~17 MB).
// MODE 0: QKV epilogue — n<768 -> qkb[m][768] bf16; n>=768 -> vtb[bh][d][tok] via LDS transpose
// MODE 1: f32 C out, row-major [M][N]
template<int MODE, int NP>
__global__ __launch_bounds__(256, 2) void gemm_bt_kernel(
    const unsigned short* __restrict__ A, const unsigned short* __restrict__ Bt,
    void* __restrict__ C0, unsigned short* __restrict__ C1,
    int M, int N, int K)
{
    __shared__ __align__(16) unsigned short Sh[3 * 128 * 64];   // As | Bs0 | Bs1, 48 KB
    unsigned short* As = Sh;
    const int tid = threadIdx.x;
    const int lane = tid & 63, wv = tid >> 6;
    const int c = lane & 15, g = lane >> 4;
    const int wm = (wv >> 1) * 64, wn = (wv & 1) * 64;

    // XCD-chunked remap, n-fastest inside chunk (grid = 8 * mpx * NP, (M/128)%8==0)
    const int mpx = (M >> 7) >> 3;
    const int id = blockIdx.x, xcd = id & 7, kk = id >> 3;
    const long m0 = (long)(xcd * mpx + kk / NP) * 128;
    const long n0 = (long)(kk % NP) * 128;

    f32x4 acc[4][4] = {};
    const int xr = (c & 7) << 4;

    // per-thread chunk geometry (4 chunks of 8 bf16 per operand)
    int chrow[4], chsc[4];
    #pragma unroll
    for (int i = 0; i < 4; ++i) {
        int ch = i * 256 + wv * 64 + lane;
        chrow[i] = ch >> 3;
        chsc[i] = ((ch & 7) ^ (chrow[i] & 7)) * 8;   // pre-swizzled source column
    }

#define STAGE_A(kt)                                                            \
    {                                                                          \
        _Pragma("unroll")                                                      \
        for (int i = 0; i < 4; ++i)                                            \
            GLOAD_LDS16(&A[(m0 + chrow[i]) * (size_t)K + (kt) + chsc[i]],      \
                        &As[(i * 256 + wv * 64) * 8]);                         \
    }
#define STAGE_B(bufofs, kt)                                                    \
    {                                                                          \
        _Pragma("unroll")                                                      \
        for (int i = 0; i < 4; ++i)                                            \
            GLOAD_LDS16(&Bt[(n0 + chrow[i]) * (size_t)K + (kt) + chsc[i]],     \
                        &Sh[(bufofs) + (i * 256 + wv * 64) * 8]);              \
    }

    STAGE_A(0);
    STAGE_B(8192, 0);
    __syncthreads();

    const int nt = K >> 6;
    for (int t = 0; t < nt; ++t) {
        const int bofs = 8192 + (t & 1) * 8192;
        if (t + 1 < nt) STAGE_B(8192 + ((t + 1) & 1) * 8192, (t + 1) * 64);  // hidden under compute
        const unsigned short* Bcur = Sh + bofs;
        #pragma unroll
        for (int ks = 0; ks < 2; ++ks) {
            short8 af[4], bf_[4];
            #pragma unroll
            for (int i = 0; i < 4; ++i)
                af[i] = *(const short8*)((char*)As +
                    (((wm + i * 16 + c) * 128 + (ks * 32 + g * 8) * 2) ^ xr));
            #pragma unroll
            for (int i = 0; i < 4; ++i)
                bf_[i] = *(const short8*)((char*)Bcur +
                    (((wn + i * 16 + c) * 128 + (ks * 32 + g * 8) * 2) ^ xr));
            #pragma unroll
            for (int mi = 0; mi < 4; ++mi)
                #pragma unroll
                for (int ni = 0; ni < 4; ++ni)
                    acc[mi][ni] = __builtin_amdgcn_mfma_f32_16x16x32_bf16(
                        af[mi], bf_[ni], acc[mi][ni], 0, 0, 0);
        }
        __syncthreads();                       // waves done with As/Bcur; B(t+1) landed
        if (t + 1 < nt) {
            STAGE_A((t + 1) * 64);             // only A's drain exposed
            __syncthreads();
        }
    }
#undef STAGE_A
#undef STAGE_B

    if (MODE == 1) {
        #pragma unroll
        for (int mi = 0; mi < 4; ++mi)
            #pragma unroll
            for (int ni = 0; ni < 4; ++ni)
                #pragma unroll
                for (int r = 0; r < 4; ++r) {
                    long m = m0 + wm + mi * 16 + g * 4 + r;
                    long n = n0 + wn + ni * 16 + c;
                    ((float*)C0)[m * N + n] = acc[mi][ni][r];
                }
    } else if (n0 < 768) {
        #pragma unroll
        for (int mi = 0; mi < 4; ++mi)
            #pragma unroll
            for (int ni = 0; ni < 4; ++ni)
                #pragma unroll
                for (int r = 0; r < 4; ++r) {
                    long m = m0 + wm + mi * 16 + g * 4 + r;
                    long n = n0 + wn + ni * 16 + c;
                    ((unsigned short*)C0)[m * 768 + n] = f2bf(acc[mi][ni][r]);
                }
    } else {
        // V block: transpose 64x64 wave subtile via private LDS region, store coalesced
        char* wbase = (char*)Sh + wv * 8192;     // Sh dead after final barrier
        #pragma unroll
        for (int ni = 0; ni < 4; ++ni)
            #pragma unroll
            for (int mi = 0; mi < 4; ++mi)
                #pragma unroll
                for (int r = 0; r < 4; ++r) {
                    int d = ni * 16 + c, t = mi * 16 + g * 4 + r;
                    int byte = (d * 128 + t * 2) ^ ((d & 7) << 4);
                    *(unsigned short*)(wbase + byte) = f2bf(acc[mi][ni][r]);
                }
        __asm__ __volatile__("" ::: "memory");
        int h = (int)((n0 + wn - 768) >> 6);
        long b = (m0 + wm) >> 8;
        int t0 = (int)((m0 + wm) & 255);
        long bh = b * 6 + h;
        #pragma unroll
        for (int it = 0; it < 8; ++it) {
            int d = it * 8 + (lane >> 3), ck = lane & 7;
            short8 v = *(const short8*)(wbase + ((d * 128 + ck * 16) ^ ((d & 7) << 4)));
            *(short8*)&C1[(bh * 64 + d) * 256 + t0 + ck * 8] = v;
        }
    }
}

// ---------------- fused causal attention: one block per (b,h), transposed pipeline ----------------
__global__ __launch_bounds__(256, 3) void attn_kernel(
    const unsigned short* __restrict__ qk,    // [B*T][768] bf16 (q|k)
    const unsigned short* __restrict__ vt,    // [B*6+h][64 d][256 tok] bf16
    unsigned short* __restrict__ outp)        // [B*T][384] bf16
{
    const int bh = blockIdx.x;
    const int b = bh / 6, h = bh - b * 6;
    const int tid = threadIdx.x;
    const int lane = tid & 63, wv = tid >> 6;
    const int c = lane & 15, g = lane >> 4;

    __shared__ unsigned short Ks[256 * 64];    // [key][d], swizzled, 32 KB
    __shared__ unsigned short Pl[4][16 * 64];  // per-wave P [q=c][k], 8 KB

    #pragma unroll
    for (int it = 0; it < 8; ++it) {
        int ch = it * 256 + tid;
        int row = ch >> 3, col = (ch & 7) * 8;
        int db = (row * 128 + col * 2) ^ ((row & 7) << 4);
        *(short8*)((char*)Ks + db) =
            *(const short8*)&qk[(size_t)(b * 256 + row) * 768 + 384 + h * 64 + col];
    }
    __syncthreads();

    char* plw = (char*)Pl[wv];

    for (int t = 0; t < 2; ++t) {
        const int p = t ? 7 - wv : wv;
        const int jlast = p >> 1;
        const int modd = (p & 1) * 32;
        const int qt0 = p * 32;

        short8 aq[2][2];
        #pragma unroll
        for (int mi = 0; mi < 2; ++mi)
            #pragma unroll
            for (int ks = 0; ks < 2; ++ks)
                aq[mi][ks] = *(const short8*)&qk[
                    (size_t)(b * 256 + qt0 + mi * 16 + c) * 768 + h * 64 + ks * 32 + g * 8];

        f32x4 o[2][4] = {};
        float mrun[2] = {-1e30f, -1e30f}, lrun[2] = {0.f, 0.f};

        for (int j = 0; j <= jlast; ++j) {
            short8 bv[4][2];
            #pragma unroll
            for (int nd = 0; nd < 4; ++nd)
                #pragma unroll
                for (int ks = 0; ks < 2; ++ks)
                    bv[nd][ks] = *(const short8*)&vt[
                        ((size_t)bh * 64 + nd * 16 + c) * 256 + j * 64 + ks * 32 + g * 8];

            short8 bk[4][2];
            #pragma unroll
            for (int ni = 0; ni < 4; ++ni)
                #pragma unroll
                for (int ks = 0; ks < 2; ++ks) {
                    int key = j * 64 + ni * 16 + c;
                    bk[ni][ks] = *(const short8*)((char*)Ks +
                        ((key * 128 + (ks * 32 + g * 8) * 2) ^ ((key & 7) << 4)));
                }

            #pragma unroll
            for (int mi = 0; mi < 2; ++mi) {
                float pv[4][4];
                #pragma unroll
                for (int ni = 0; ni < 4; ++ni) {
                    f32x4 z = {0.f, 0.f, 0.f, 0.f};
                    z = __builtin_amdgcn_mfma_f32_16x16x32_bf16(bk[ni][0], aq[mi][0], z, 0, 0, 0);
                    z = __builtin_amdgcn_mfma_f32_16x16x32_bf16(bk[ni][1], aq[mi][1], z, 0, 0, 0);
                    #pragma unroll
                    for (int r = 0; r < 4; ++r) {
                        float v = z[r] * 0.125f;
                        if (j == jlast) {
                            int kloc = ni * 16 + g * 4 + r;
                            int qloc = mi * 16 + c + modd;
                            if (kloc > qloc) v = -1e30f;
                        }
                        pv[ni][r] = v;
                    }
                }
                float m01 = fmaxf(fmaxf(pv[0][0], pv[0][1]), fmaxf(pv[0][2], pv[0][3]));
                float m11 = fmaxf(fmaxf(pv[1][0], pv[1][1]), fmaxf(pv[1][2], pv[1][3]));
                float m21 = fmaxf(fmaxf(pv[2][0], pv[2][1]), fmaxf(pv[2][2], pv[2][3]));
                float m31 = fmaxf(fmaxf(pv[3][0], pv[3][1]), fmaxf(pv[3][2], pv[3][3]));
                float m1 = fmaxf(fmaxf(m01, m11), fmaxf(m21, m31));
                m1 = fmaxf(m1, __shfl_xor(m1, 16));
                m1 = fmaxf(m1, __shfl_xor(m1, 32));
                float mold = mrun[mi];
                float mnew = fmaxf(mold, m1);
                float fac = __expf(mold - mnew);
                float ssum = 0.f;
                #pragma unroll
                for (int ni = 0; ni < 4; ++ni)
                    #pragma unroll
                    for (int r = 0; r < 4; ++r) {
                        float pp = __expf(pv[ni][r] - mnew);
                        pv[ni][r] = pp;
                        ssum += pp;
                    }
                ssum += __shfl_xor(ssum, 16);
                ssum += __shfl_xor(ssum, 32);
                lrun[mi] = lrun[mi] * fac + ssum;
                mrun[mi] = mnew;
                #pragma unroll
                for (int nd = 0; nd < 4; ++nd)
                    #pragma unroll
                    for (int r = 0; r < 4; ++r) o[mi][nd][r] *= fac;

                __asm__ __volatile__("" ::: "memory");
                #pragma unroll
                for (int ni = 0; ni < 4; ++ni) {
                    uint2 w;
                    w.x = pk2(pv[ni][0], pv[ni][1]);
                    w.y = pk2(pv[ni][2], pv[ni][3]);
                    *(uint2*)(plw + ((c * 128 + ni * 32 + g * 8) ^ ((c & 7) << 4))) = w;
                }
                __asm__ __volatile__("" ::: "memory");

                short8 ap[2];
                #pragma unroll
                for (int ks = 0; ks < 2; ++ks)
                    ap[ks] = *(const short8*)(plw +
                        ((c * 128 + ks * 64 + g * 16) ^ ((c & 7) << 4)));

                #pragma unroll
                for (int nd = 0; nd < 4; ++nd) {
                    o[mi][nd] = __builtin_amdgcn_mfma_f32_16x16x32_bf16(bv[nd][0], ap[0], o[mi][nd], 0, 0, 0);
                    o[mi][nd] = __builtin_amdgcn_mfma_f32_16x16x32_bf16(bv[nd][1], ap[1], o[mi][nd], 0, 0, 0);
                }
                __asm__ __volatile__("" ::: "memory");
            }
        }

        #pragma unroll
        for (int mi = 0; mi < 2; ++mi) {
            float inv = 1.0f / lrun[mi];
            #pragma unroll
            for (int nd = 0; nd < 4; ++nd) {
                ush4 w;
                #pragma unroll
                for (int r = 0; r < 4; ++r) w[r] = f2bf(o[mi][nd][r] * inv);
                *(ush4*)&outp[((size_t)b * 256 + qt0 + mi * 16 + c) * 384 + h * 64 + nd * 16 + g * 4] = w;
            }
        }
    }
}

extern "C" void kernel_launch(void* const* d_in, const int* in_sizes, int n_in,
                              void* d_out, int out_size, void* d_ws, size_t ws_size,
                              hipStream_t stream) {
    const float* x     = (const float*)d_in[0];   // [128,256,384] f32
    const float* Wqkv  = (const float*)d_in[1];   // [384,1152] f32
    const float* Wproj = (const float*)d_in[2];   // [384,384] f32

    char* ws = (char*)d_ws;
    unsigned short* xb     = (unsigned short*)(ws);                 // 25,165,824 B
    unsigned short* wqkvt  = (unsigned short*)(ws + 25165824);      //    884,736 B
    unsigned short* wprojt = (unsigned short*)(ws + 26050560);      //    294,912 B
    unsigned short* qkb    = (unsigned short*)(ws + 26345472);      // 50,331,648 B  [tok][768]
    unsigned short* vtb    = (unsigned short*)(ws + 76677120);      // 25,165,824 B  [bh][64][256]
    unsigned short* attnb  = (unsigned short*)(ws + 101842944);     // 25,165,824 B
    // total: 127,008,768 B

    cast_all_kernel<<<8448, 256, 0, stream>>>(x, Wqkv, Wproj, xb, wqkvt, wprojt);

    gemm_bt_kernel<0, 9><<<2304, 256, 0, stream>>>(xb, wqkvt, (void*)qkb, vtb, 32768, 1152, 384);
    attn_kernel<<<768, 256, 0, stream>>>(qkb, vtb, attnb);
    gemm_bt_kernel<1, 3><<<768, 256, 0, stream>>>(attnb, wprojt, d_out, nullptr, 32768, 384, 384);
}